// Round 3
// baseline (379.262 us; speedup 1.0000x reference)
//
#include <hip/hip_runtime.h>
#include <stdint.h>

// Problem constants (B,N,D,H fixed by setup_inputs)
#define B_  8
#define N_  768
#define D_  2048
#define H_  4
#define HN  192   // head width n = N/H

typedef unsigned short u16;
typedef float    f32x4 __attribute__((ext_vector_type(4)));
typedef __bf16   bf16x8 __attribute__((ext_vector_type(8)));
typedef uint32_t u32x4 __attribute__((ext_vector_type(4)));
typedef uint32_t u32x2 __attribute__((ext_vector_type(2)));

__device__ __forceinline__ u16 f2bf(float f) {
  uint32_t u = __builtin_bit_cast(uint32_t, f);
  u += 0x7fffu + ((u >> 16) & 1u);   // round-to-nearest-even
  return (u16)(u >> 16);
}

// async global->LDS DMA, 16 B per lane; LDS dest = uniform base + lane*16
typedef const __attribute__((address_space(1))) void* gas_ptr;
typedef __attribute__((address_space(3))) void* las_ptr;
__device__ __forceinline__ void gld16(const void* g, void* l) {
  __builtin_amdgcn_global_load_lds((gas_ptr)g, (las_ptr)l, 16, 0, 0);
}

// ---------------------------------------------------------------------------
// Kernel 0: transpose x (B,N,D) fp32 -> xt (B,D,N) bf16
// ---------------------------------------------------------------------------
__global__ __launch_bounds__(256) void transpose_x(const float* __restrict__ x,
                                                   u16* __restrict__ xt) {
  __shared__ float tile[64][65];
  const int d0 = blockIdx.x * 64;
  const int n0 = blockIdx.y * 64;
  const int b  = blockIdx.z;
  const int t   = threadIdx.x;
  const int col = t & 63;
  const int rb  = (t >> 6) * 16;
  const float* src = x + ((size_t)b * N_ + n0) * D_ + d0;
  #pragma unroll
  for (int i = 0; i < 16; i++)
    tile[rb + i][col] = src[(size_t)(rb + i) * D_ + col];
  __syncthreads();
  u16* dst = xt + ((size_t)b * D_ + d0) * N_ + n0;
  #pragma unroll
  for (int i = 0; i < 16; i++)
    dst[(size_t)(rb + i) * N_ + col] = f2bf(tile[col][rb + i]);
}

// ---------------------------------------------------------------------------
// Kernel 0b: convert the three weight matrices fp32 -> bf16
// ---------------------------------------------------------------------------
__global__ __launch_bounds__(256) void cvt_w(const float* __restrict__ a,
                                             const float* __restrict__ b,
                                             const float* __restrict__ c,
                                             u16* __restrict__ oa,
                                             u16* __restrict__ ob,
                                             u16* __restrict__ oc) {
  const float* src = (blockIdx.y == 0) ? a : ((blockIdx.y == 1) ? b : c);
  u16*         dst = (blockIdx.y == 0) ? oa : ((blockIdx.y == 1) ? ob : oc);
  const int i = (blockIdx.x * 256 + threadIdx.x) * 4;
  f32x4 v = *(const f32x4*)(src + i);
  u16 tmp[4];
  #pragma unroll
  for (int j = 0; j < 4; j++) tmp[j] = f2bf(v[j]);
  *(u32x2*)(dst + i) = *(u32x2*)tmp;
}

// ---------------------------------------------------------------------------
// Kernel 0c: zero the q2 accumulator (ws is poisoned 0xAA each launch)
// ---------------------------------------------------------------------------
__global__ __launch_bounds__(256) void zero_q2(float* __restrict__ q2) {
  q2[blockIdx.x * 256 + threadIdx.x] = 0.f;
}

// ---------------------------------------------------------------------------
// Kernel 1: fused QK/V GEMM, outputs in fragment-tiled layout.
//   qkb[bh][dtile][jn8 24][d_local 64][8]   (bf16)  -- serves attn Q and K
//   vtb[bh][etile][e8 8][jn 192][8]         (bf16)  -- serves attn V
//   q2[bh,d] += sum_jn qk^2                  (fp32 atomics)
// Block: 64(d) x 64(j) tile, BK=32, 4 waves (2x2), 16x16x32 bf16 MFMA.
// ---------------------------------------------------------------------------
__global__ __launch_bounds__(256) void qkv_gemm(const u16* __restrict__ xt,
                                                const u16* __restrict__ wqk,
                                                const u16* __restrict__ wv,
                                                u16* __restrict__ qkb,
                                                u16* __restrict__ vtb,
                                                float* __restrict__ q2) {
  const int b  = blockIdx.z;
  const int dtile = blockIdx.x;
  const int d0 = dtile * 64;
  const int j0 = blockIdx.y * 64;
  const int h   = j0 / HN;          // 64-tile never straddles a head (192=3*64)
  const int jn0 = j0 - h * HN;
  const int tid  = threadIdx.x;
  const int wave = tid >> 6, lane = tid & 63;
  const int l15  = lane & 15, quad = lane >> 4;
  const int wm = wave >> 1, wn = wave & 1;

  __shared__ u16 At[64][40];   // +8 pad
  __shared__ u16 Bq[64][40];
  __shared__ u16 Bv[64][40];
  __shared__ float ttile[64][76];  // epilogue transpose buffer (stride 76 ≡ 12 mod 32)

  const f32x4 fz = {0.f, 0.f, 0.f, 0.f};
  f32x4 accq[2][2], accv[2][2];
  #pragma unroll
  for (int i = 0; i < 2; i++)
    #pragma unroll
    for (int j = 0; j < 2; j++) { accq[i][j] = fz; accv[i][j] = fz; }

  const int srow = tid >> 2;
  const int soff = (tid & 3) * 8;
  const u16* ax = xt  + ((size_t)b * D_ + d0 + srow) * N_ + soff;
  const u16* bq = wqk + (size_t)(j0 + srow) * N_ + soff;
  const u16* bv = wv  + (size_t)(j0 + srow) * N_ + soff;

  for (int k0 = 0; k0 < N_; k0 += 32) {
    __syncthreads();
    *(u32x4*)&At[srow][soff] = *(const u32x4*)(ax + k0);
    *(u32x4*)&Bq[srow][soff] = *(const u32x4*)(bq + k0);
    *(u32x4*)&Bv[srow][soff] = *(const u32x4*)(bv + k0);
    __syncthreads();
    bf16x8 Af[2], Bqf[2], Bvf[2];
    #pragma unroll
    for (int mi = 0; mi < 2; mi++)
      Af[mi] = *(const bf16x8*)&At[wm * 32 + mi * 16 + l15][quad * 8];
    #pragma unroll
    for (int ni = 0; ni < 2; ni++) {
      Bqf[ni] = *(const bf16x8*)&Bq[wn * 32 + ni * 16 + l15][quad * 8];
      Bvf[ni] = *(const bf16x8*)&Bv[wn * 32 + ni * 16 + l15][quad * 8];
    }
    #pragma unroll
    for (int mi = 0; mi < 2; mi++)
      #pragma unroll
      for (int ni = 0; ni < 2; ni++) {
        accq[mi][ni] = __builtin_amdgcn_mfma_f32_16x16x32_bf16(Af[mi], Bqf[ni], accq[mi][ni], 0, 0, 0);
        accv[mi][ni] = __builtin_amdgcn_mfma_f32_16x16x32_bf16(Af[mi], Bvf[ni], accv[mi][ni], 0, 0, 0);
      }
  }

  const size_t bh = (size_t)(b * H_ + h);

  // q2 partial sums (C layout: col=lane&15, row=quad*4+r)
  #pragma unroll
  for (int mi = 0; mi < 2; mi++)
    #pragma unroll
    for (int r = 0; r < 4; r++) {
      const int d = d0 + wm * 32 + mi * 16 + quad * 4 + r;
      float ssq = 0.f;
      #pragma unroll
      for (int ni = 0; ni < 2; ni++) {
        float val = accq[mi][ni][r];
        ssq += val * val;
      }
      ssq += __shfl_xor(ssq, 1, 64);
      ssq += __shfl_xor(ssq, 2, 64);
      ssq += __shfl_xor(ssq, 4, 64);
      ssq += __shfl_xor(ssq, 8, 64);
      if (l15 == 0) atomicAdd(&q2[bh * D_ + d], ssq);
    }

  // ---- qk epilogue: LDS transpose -> fragment-tiled store ----
  // ttile[d_local][jn_local]
  #pragma unroll
  for (int mi = 0; mi < 2; mi++)
    #pragma unroll
    for (int ni = 0; ni < 2; ni++)
      #pragma unroll
      for (int r = 0; r < 4; r++)
        ttile[wm * 32 + mi * 16 + quad * 4 + r][wn * 32 + ni * 16 + l15] = accq[mi][ni][r];
  __syncthreads();
  u16* qtbase = qkb + bh * (size_t)(D_ * HN) + (size_t)dtile * 12288 + (size_t)(jn0 >> 3) * 512;
  #pragma unroll
  for (int i = 0; i < 2; i++) {
    const int p = tid + i * 256;
    const int d = p & 63, g8 = p >> 6;     // g8 in [0,8): jn8 group within this 64-col block
    u16 tmp[8];
    #pragma unroll
    for (int j = 0; j < 8; j++) tmp[j] = f2bf(ttile[d][g8 * 8 + j]);
    *(u32x4*)(qtbase + (size_t)(g8 * 64 + d) * 8) = *(u32x4*)tmp;
  }
  __syncthreads();

  // ---- v epilogue: ttile[jn_local][d_local] -> fragment-tiled store ----
  #pragma unroll
  for (int mi = 0; mi < 2; mi++)
    #pragma unroll
    for (int ni = 0; ni < 2; ni++)
      *(f32x4*)&ttile[wn * 32 + ni * 16 + l15][wm * 32 + mi * 16 + quad * 4] = accv[mi][ni];
  __syncthreads();
  u16* vtbase = vtb + bh * (size_t)(D_ * HN) + (size_t)dtile * 12288;
  #pragma unroll
  for (int i = 0; i < 2; i++) {
    const int p = tid + i * 256;
    const int jn = p & 63, d8 = p >> 6;    // d8 = e8 group
    u16 tmp[8];
    #pragma unroll
    for (int j = 0; j < 8; j++) tmp[j] = f2bf(ttile[jn][d8 * 8 + j]);
    *(u32x4*)(vtbase + (size_t)(d8 * 192 + jn0 + jn) * 8) = *(u32x4*)tmp;
  }
}

// ---------------------------------------------------------------------------
// Kernel 2: fused attention v3, analytic-max softmax.
//   p(d,e) = exp(2*QK - q2[e] - q2[d])  (row max = diagonal, known a priori)
//   O = (P @ V) / rowsum ; written merged-head to wbuf (B,D,N) bf16.
// Block: one (b,h), 256 Q-rows; wave = 64 rows (one dtile), 4 waves.
// Grid 256 = 8 d-blocks x 32 bh, 1 block/CU, double-buffered K/V DMA.
// Every K/V fragment read from LDS is amortized over 64 Q-rows.
// ---------------------------------------------------------------------------
__global__ __launch_bounds__(256, 1) void attn_kernel(const u16* __restrict__ qkb,
                                                      const u16* __restrict__ vtb,
                                                      const float* __restrict__ q2,
                                                      u16* __restrict__ wbuf) {
  const int bid  = blockIdx.x;
  const int xcd  = bid & 7;
  const int rest = bid >> 3;
  const int blk  = rest & 7;             // 256-row d-block
  const int bh   = xcd + 8 * (rest >> 3); // all 8 blocks of a bh on one XCD
  const int b = bh >> 2, h = bh & 3;
  const int tid  = threadIdx.x;
  const int wave = tid >> 6, lane = tid & 63;
  const int l15  = lane & 15, quad = lane >> 4;

  __shared__ u16 Klds[2][12288];   // [jn8 24][e 64][8], DMA-linear, ping-pong
  __shared__ u16 Vlds[2][12288];   // [e8 8][jn 192][8], DMA-linear, ping-pong
  __shared__ u16 Pl[4][64][72];    // per-wave P round-trip (C->A layout), padded

  const u16* kbase = qkb + (size_t)bh * (D_ * HN);
  const u16* vbase = vtb + (size_t)bh * (D_ * HN);
  const float* q2g = q2 + (size_t)bh * D_;

  // DMA tile 0 into buffer 0 (each wave stages a quarter)
  {
    const u16* kt = kbase + wave * 3072 + lane * 8;
    const u16* vt = vbase + wave * 3072 + lane * 8;
    #pragma unroll
    for (int i = 0; i < 6; i++) {
      gld16(kt + i * 512, &Klds[0][wave * 3072 + i * 512]);
      gld16(vt + i * 512, &Vlds[0][wave * 3072 + i * 512]);
    }
  }

  // Q fragments (A layout): wave owns dtile = blk*4 + wave (64 rows x 192)
  const int dtile = blk * 4 + wave;
  bf16x8 Qf[4][6];
  {
    const u16* qt = kbase + (size_t)dtile * 12288 + (size_t)quad * 512 + (size_t)l15 * 8;
    #pragma unroll
    for (int gg = 0; gg < 4; gg++)
      #pragma unroll
      for (int f = 0; f < 6; f++)
        Qf[gg][f] = *(const bf16x8*)(qt + f * 2048 + gg * 128);
  }
  // row biases q2[d] (constant over loop — analytic max)
  float cd[4][4];
  #pragma unroll
  for (int gg = 0; gg < 4; gg++)
    #pragma unroll
    for (int r = 0; r < 4; r++)
      cd[gg][r] = q2g[blk * 256 + wave * 64 + gg * 16 + quad * 4 + r];

  const f32x4 fz = {0.f, 0.f, 0.f, 0.f};
  f32x4 O[4][12];
  #pragma unroll
  for (int gg = 0; gg < 4; gg++)
    #pragma unroll
    for (int c = 0; c < 12; c++) O[gg][c] = fz;
  float rs[4][4];
  #pragma unroll
  for (int gg = 0; gg < 4; gg++)
    #pragma unroll
    for (int r = 0; r < 4; r++) rs[gg][r] = 0.f;

  for (int t = 0; t < 32; t++) {
    const int cur = t & 1;
    // Drain this wave's DMA (issued a full iter ago -> complete) and protect
    // the buffer about to be overwritten (all waves past their reads).
    __syncthreads();
    // column biases for this tile (issued before next DMA so their drain is cheap)
    float ce[4];
    #pragma unroll
    for (int ni = 0; ni < 4; ni++) ce[ni] = q2g[t * 64 + ni * 16 + l15];
    // prefetch tile t+1 into the other buffer; lands during compute below
    if (t < 31) {
      const u16* kt = kbase + (size_t)(t + 1) * 12288 + wave * 3072 + lane * 8;
      const u16* vt = vbase + (size_t)(t + 1) * 12288 + wave * 3072 + lane * 8;
      #pragma unroll
      for (int i = 0; i < 6; i++) {
        gld16(kt + i * 512, &Klds[1 - cur][wave * 3072 + i * 512]);
        gld16(vt + i * 512, &Vlds[1 - cur][wave * 3072 + i * 512]);
      }
    }

    // ---- S = Q K^T, exp, P write --- per 16-col group ni ----
    #pragma unroll
    for (int ni = 0; ni < 4; ni++) {
      bf16x8 Kf[6];
      #pragma unroll
      for (int f = 0; f < 6; f++)
        Kf[f] = *(const bf16x8*)&Klds[cur][(f * 4 + quad) * 512 + (ni * 16 + l15) * 8];
      f32x4 S[4];
      #pragma unroll
      for (int gg = 0; gg < 4; gg++) {
        f32x4 acc = fz;
        #pragma unroll
        for (int f = 0; f < 6; f++)
          acc = __builtin_amdgcn_mfma_f32_16x16x32_bf16(Qf[gg][f], Kf[f], acc, 0, 0, 0);
        S[gg] = acc;
      }
      #pragma unroll
      for (int gg = 0; gg < 4; gg++)
        #pragma unroll
        for (int r = 0; r < 4; r++) {
          float p = __expf(__builtin_fmaf(S[gg][r], 2.f, -(ce[ni] + cd[gg][r])));
          rs[gg][r] += p;
          Pl[wave][gg * 16 + quad * 4 + r][ni * 16 + l15] = f2bf(p);
        }
    }

    // ---- O += P V : V fragments shared across all 4 row groups ----
    bf16x8 Pf[4][2];
    #pragma unroll
    for (int gg = 0; gg < 4; gg++)
      #pragma unroll
      for (int kk = 0; kk < 2; kk++)
        Pf[gg][kk] = *(const bf16x8*)&Pl[wave][gg * 16 + l15][kk * 32 + quad * 8];
    #pragma unroll
    for (int kk = 0; kk < 2; kk++)
      #pragma unroll
      for (int c = 0; c < 12; c++) {
        bf16x8 Vf = *(const bf16x8*)&Vlds[cur][((kk * 4 + quad) * 192 + c * 16 + l15) * 8];
        #pragma unroll
        for (int gg = 0; gg < 4; gg++)
          O[gg][c] = __builtin_amdgcn_mfma_f32_16x16x32_bf16(Pf[gg][kk], Vf, O[gg][c], 0, 0, 0);
      }
  }

  // reduce row sums across the 16 column-lanes, once
  #pragma unroll
  for (int gg = 0; gg < 4; gg++)
    #pragma unroll
    for (int r = 0; r < 4; r++) {
      float s = rs[gg][r];
      s += __shfl_xor(s, 1, 64);
      s += __shfl_xor(s, 2, 64);
      s += __shfl_xor(s, 4, 64);
      s += __shfl_xor(s, 8, 64);
      rs[gg][r] = s;
    }

  // normalize + merged-head store: wbuf[b, d, h*192 + col] bf16
  #pragma unroll
  for (int gg = 0; gg < 4; gg++)
    #pragma unroll
    for (int r = 0; r < 4; r++) {
      const float inv = 1.f / rs[gg][r];
      const int d = blk * 256 + wave * 64 + gg * 16 + quad * 4 + r;
      u16* wrow = wbuf + ((size_t)b * D_ + d) * N_ + h * HN;
      #pragma unroll
      for (int c = 0; c < 12; c++)
        wrow[c * 16 + l15] = f2bf(O[gg][c][r] * inv);
    }
}

// ---------------------------------------------------------------------------
// Kernel 3: out GEMM + transpose.  out[b,i,d] = sum_j w[b,d,j]*Wout[i,j] (fp32)
// ---------------------------------------------------------------------------
__global__ __launch_bounds__(256) void out_gemm(const u16* __restrict__ wbuf,
                                                const u16* __restrict__ wout,
                                                float* __restrict__ outp) {
  const int b  = blockIdx.z;
  const int d0 = blockIdx.x * 64;
  const int i0 = blockIdx.y * 64;
  const int tid  = threadIdx.x;
  const int wave = tid >> 6, lane = tid & 63;
  const int l15  = lane & 15, quad = lane >> 4;
  const int wm = wave >> 1, wn = wave & 1;

  __shared__ u16 At[64][40];
  __shared__ u16 Bt[64][40];
  __shared__ float otile[64][68];

  const f32x4 fz = {0.f, 0.f, 0.f, 0.f};
  f32x4 acc[2][2];
  #pragma unroll
  for (int i = 0; i < 2; i++)
    #pragma unroll
    for (int j = 0; j < 2; j++) acc[i][j] = fz;

  const int srow = tid >> 2;
  const int soff = (tid & 3) * 8;
  const u16* ax = wbuf + ((size_t)b * D_ + d0 + srow) * N_ + soff;
  const u16* bw = wout + (size_t)(i0 + srow) * N_ + soff;

  for (int k0 = 0; k0 < N_; k0 += 32) {
    __syncthreads();
    *(u32x4*)&At[srow][soff] = *(const u32x4*)(ax + k0);
    *(u32x4*)&Bt[srow][soff] = *(const u32x4*)(bw + k0);
    __syncthreads();
    bf16x8 Af[2], Bf[2];
    #pragma unroll
    for (int mi = 0; mi < 2; mi++)
      Af[mi] = *(const bf16x8*)&At[wm * 32 + mi * 16 + l15][quad * 8];
    #pragma unroll
    for (int ni = 0; ni < 2; ni++)
      Bf[ni] = *(const bf16x8*)&Bt[wn * 32 + ni * 16 + l15][quad * 8];
    #pragma unroll
    for (int mi = 0; mi < 2; mi++)
      #pragma unroll
      for (int ni = 0; ni < 2; ni++)
        acc[mi][ni] = __builtin_amdgcn_mfma_f32_16x16x32_bf16(Af[mi], Bf[ni], acc[mi][ni], 0, 0, 0);
  }

  #pragma unroll
  for (int mi = 0; mi < 2; mi++)
    #pragma unroll
    for (int ni = 0; ni < 2; ni++)
      #pragma unroll
      for (int r = 0; r < 4; r++)
        otile[wn * 32 + ni * 16 + l15][wm * 32 + mi * 16 + quad * 4 + r] = acc[mi][ni][r];
  __syncthreads();
  const int il = tid >> 2;
  const int ch = (tid & 3) * 16;
  float* orow = outp + ((size_t)b * N_ + i0 + il) * D_ + d0 + ch;
  #pragma unroll
  for (int i = 0; i < 16; i += 4)
    *(f32x4*)(orow + i) = *(const f32x4*)&otile[il][ch + i];
}

// ---------------------------------------------------------------------------
extern "C" void kernel_launch(void* const* d_in, const int* in_sizes, int n_in,
                              void* d_out, int out_size, void* d_ws, size_t ws_size,
                              hipStream_t stream) {
  (void)in_sizes; (void)n_in; (void)out_size; (void)ws_size;
  const float* x    = (const float*)d_in[0];
  const float* Wqk  = (const float*)d_in[1];
  const float* Wv   = (const float*)d_in[2];
  const float* Wout = (const float*)d_in[3];
  float* outp = (float*)d_out;

  // Workspace layout (~79 MB total; all offsets 16B-aligned)
  char* ws = (char*)d_ws;
  size_t off = 0;
  u16* xt   = (u16*)(ws + off); off += (size_t)B_ * D_ * N_ * 2;        // 25.2 MB
  u16* qkb  = (u16*)(ws + off); off += (size_t)B_ * H_ * D_ * HN * 2;   // 25.2 MB
  u16* vtb  = (u16*)(ws + off); off += (size_t)B_ * H_ * HN * D_ * 2;   // 25.2 MB
  float* q2 = (float*)(ws + off); off += (size_t)B_ * H_ * D_ * 4;      // 256 KB
  u16* wqk_bf  = (u16*)(ws + off); off += (size_t)N_ * N_ * 2;
  u16* wv_bf   = (u16*)(ws + off); off += (size_t)N_ * N_ * 2;
  u16* wout_bf = (u16*)(ws + off); off += (size_t)N_ * N_ * 2;
  u16* wbuf = xt;   // xt dead after qkv_gemm; reuse for attention output

  transpose_x<<<dim3(D_ / 64, N_ / 64, B_), 256, 0, stream>>>(x, xt);
  cvt_w<<<dim3((N_ * N_) / (256 * 4), 3), 256, 0, stream>>>(Wqk, Wv, Wout, wqk_bf, wv_bf, wout_bf);
  zero_q2<<<dim3((B_ * H_ * D_) / 256), 256, 0, stream>>>(q2);
  qkv_gemm<<<dim3(D_ / 64, N_ / 64, B_), 256, 0, stream>>>(xt, wqk_bf, wv_bf, qkb, vtb, q2);
  attn_kernel<<<dim3((D_ / 256) * B_ * H_), 256, 0, stream>>>(qkb, vtb, q2, wbuf);
  out_gemm<<<dim3(D_ / 64, N_ / 64, B_), 256, 0, stream>>>(wbuf, wout_bf, outp);
}

// Round 4
// 347.307 us; speedup vs baseline: 1.0920x; 1.0920x over previous
//
#include <hip/hip_runtime.h>
#include <stdint.h>

// Problem constants (B,N,D,H fixed by setup_inputs)
#define B_  8
#define N_  768
#define D_  2048
#define H_  4
#define HN  192   // head width n = N/H

// padded global/LDS layouts for attention (conflict-free DMA-linear)
#define QROW 200          // K/Q row: 192 + 8 pad u16  -> 400 B (≡4 banks)
#define VROW 72           // V row: 64 + 8 pad u16     -> 144 B (≡4 banks)
#define KTILE_B 25600     // 64 * 400 B
#define VTILE_B 27648     // 192 * 144 B

typedef unsigned short u16;
typedef float    f32x4 __attribute__((ext_vector_type(4)));
typedef __bf16   bf16x8 __attribute__((ext_vector_type(8)));
typedef uint32_t u32x4 __attribute__((ext_vector_type(4)));
typedef uint32_t u32x2 __attribute__((ext_vector_type(2)));

__device__ __forceinline__ u16 f2bf(float f) {
  uint32_t u = __builtin_bit_cast(uint32_t, f);
  u += 0x7fffu + ((u >> 16) & 1u);   // round-to-nearest-even
  return (u16)(u >> 16);
}

// async global->LDS DMA, 16 B per lane; LDS dest = uniform base + lane*16
typedef const __attribute__((address_space(1))) void* gas_ptr;
typedef __attribute__((address_space(3))) void* las_ptr;
__device__ __forceinline__ void gld16(const void* g, void* l) {
  __builtin_amdgcn_global_load_lds((gas_ptr)g, (las_ptr)l, 16, 0, 0);
}

// ---------------------------------------------------------------------------
// Kernel 0: transpose x (B,N,D) fp32 -> xt (B,D,N) bf16
// ---------------------------------------------------------------------------
__global__ __launch_bounds__(256) void transpose_x(const float* __restrict__ x,
                                                   u16* __restrict__ xt) {
  __shared__ float tile[64][65];
  const int d0 = blockIdx.x * 64;
  const int n0 = blockIdx.y * 64;
  const int b  = blockIdx.z;
  const int t   = threadIdx.x;
  const int col = t & 63;
  const int rb  = (t >> 6) * 16;
  const float* src = x + ((size_t)b * N_ + n0) * D_ + d0;
  #pragma unroll
  for (int i = 0; i < 16; i++)
    tile[rb + i][col] = src[(size_t)(rb + i) * D_ + col];
  __syncthreads();
  u16* dst = xt + ((size_t)b * D_ + d0) * N_ + n0;
  #pragma unroll
  for (int i = 0; i < 16; i++)
    dst[(size_t)(rb + i) * N_ + col] = f2bf(tile[col][rb + i]);
}

// ---------------------------------------------------------------------------
// Kernel 0b: convert the three weight matrices fp32 -> bf16
// ---------------------------------------------------------------------------
__global__ __launch_bounds__(256) void cvt_w(const float* __restrict__ a,
                                             const float* __restrict__ b,
                                             const float* __restrict__ c,
                                             u16* __restrict__ oa,
                                             u16* __restrict__ ob,
                                             u16* __restrict__ oc) {
  const float* src = (blockIdx.y == 0) ? a : ((blockIdx.y == 1) ? b : c);
  u16*         dst = (blockIdx.y == 0) ? oa : ((blockIdx.y == 1) ? ob : oc);
  const int i = (blockIdx.x * 256 + threadIdx.x) * 4;
  f32x4 v = *(const f32x4*)(src + i);
  u16 tmp[4];
  #pragma unroll
  for (int j = 0; j < 4; j++) tmp[j] = f2bf(v[j]);
  *(u32x2*)(dst + i) = *(u32x2*)tmp;
}

// ---------------------------------------------------------------------------
// Kernel 0c: zero the q2 accumulator (ws is poisoned 0xAA each launch)
// ---------------------------------------------------------------------------
__global__ __launch_bounds__(256) void zero_q2(float* __restrict__ q2) {
  q2[blockIdx.x * 256 + threadIdx.x] = 0.f;
}

// ---------------------------------------------------------------------------
// Kernel 1: fused QK/V GEMM.
//   qkb[bh][d 2048][QROW]       row-major qk rows (192 data + 8 pad u16)
//   vtb[bh][etile 32][jn 192][VROW]  V^T tiles (64 e data + 8 pad u16)
//   q2[bh,d] += sum_jn qk^2     (fp32 atomics)
// Block: 64(d) x 64(j) tile, BK=32, 4 waves (2x2), 16x16x32 bf16 MFMA.
// ---------------------------------------------------------------------------
__global__ __launch_bounds__(256) void qkv_gemm(const u16* __restrict__ xt,
                                                const u16* __restrict__ wqk,
                                                const u16* __restrict__ wv,
                                                u16* __restrict__ qkb,
                                                u16* __restrict__ vtb,
                                                float* __restrict__ q2) {
  const int b  = blockIdx.z;
  const int dtile = blockIdx.x;
  const int d0 = dtile * 64;
  const int j0 = blockIdx.y * 64;
  const int h   = j0 / HN;          // 64-tile never straddles a head (192=3*64)
  const int jn0 = j0 - h * HN;
  const int tid  = threadIdx.x;
  const int wave = tid >> 6, lane = tid & 63;
  const int l15  = lane & 15, quad = lane >> 4;
  const int wm = wave >> 1, wn = wave & 1;

  __shared__ u16 At[64][40];   // +8 pad
  __shared__ u16 Bq[64][40];
  __shared__ u16 Bv[64][40];
  __shared__ float ttile[64][76];  // epilogue transpose buffer

  const f32x4 fz = {0.f, 0.f, 0.f, 0.f};
  f32x4 accq[2][2], accv[2][2];
  #pragma unroll
  for (int i = 0; i < 2; i++)
    #pragma unroll
    for (int j = 0; j < 2; j++) { accq[i][j] = fz; accv[i][j] = fz; }

  const int srow = tid >> 2;
  const int soff = (tid & 3) * 8;
  const u16* ax = xt  + ((size_t)b * D_ + d0 + srow) * N_ + soff;
  const u16* bq = wqk + (size_t)(j0 + srow) * N_ + soff;
  const u16* bv = wv  + (size_t)(j0 + srow) * N_ + soff;

  for (int k0 = 0; k0 < N_; k0 += 32) {
    __syncthreads();
    *(u32x4*)&At[srow][soff] = *(const u32x4*)(ax + k0);
    *(u32x4*)&Bq[srow][soff] = *(const u32x4*)(bq + k0);
    *(u32x4*)&Bv[srow][soff] = *(const u32x4*)(bv + k0);
    __syncthreads();
    bf16x8 Af[2], Bqf[2], Bvf[2];
    #pragma unroll
    for (int mi = 0; mi < 2; mi++)
      Af[mi] = *(const bf16x8*)&At[wm * 32 + mi * 16 + l15][quad * 8];
    #pragma unroll
    for (int ni = 0; ni < 2; ni++) {
      Bqf[ni] = *(const bf16x8*)&Bq[wn * 32 + ni * 16 + l15][quad * 8];
      Bvf[ni] = *(const bf16x8*)&Bv[wn * 32 + ni * 16 + l15][quad * 8];
    }
    #pragma unroll
    for (int mi = 0; mi < 2; mi++)
      #pragma unroll
      for (int ni = 0; ni < 2; ni++) {
        accq[mi][ni] = __builtin_amdgcn_mfma_f32_16x16x32_bf16(Af[mi], Bqf[ni], accq[mi][ni], 0, 0, 0);
        accv[mi][ni] = __builtin_amdgcn_mfma_f32_16x16x32_bf16(Af[mi], Bvf[ni], accv[mi][ni], 0, 0, 0);
      }
  }

  const size_t bh = (size_t)(b * H_ + h);

  // q2 partial sums (C layout: col=lane&15, row=quad*4+r)
  #pragma unroll
  for (int mi = 0; mi < 2; mi++)
    #pragma unroll
    for (int r = 0; r < 4; r++) {
      const int d = d0 + wm * 32 + mi * 16 + quad * 4 + r;
      float ssq = 0.f;
      #pragma unroll
      for (int ni = 0; ni < 2; ni++) {
        float val = accq[mi][ni][r];
        ssq += val * val;
      }
      ssq += __shfl_xor(ssq, 1, 64);
      ssq += __shfl_xor(ssq, 2, 64);
      ssq += __shfl_xor(ssq, 4, 64);
      ssq += __shfl_xor(ssq, 8, 64);
      if (l15 == 0) atomicAdd(&q2[bh * D_ + d], ssq);
    }

  // ---- qk epilogue: LDS transpose -> padded row-major store ----
  #pragma unroll
  for (int mi = 0; mi < 2; mi++)
    #pragma unroll
    for (int ni = 0; ni < 2; ni++)
      #pragma unroll
      for (int r = 0; r < 4; r++)
        ttile[wm * 32 + mi * 16 + quad * 4 + r][wn * 32 + ni * 16 + l15] = accq[mi][ni][r];
  __syncthreads();
  u16* qtbase = qkb + bh * (size_t)(D_ * QROW);
  #pragma unroll
  for (int i = 0; i < 2; i++) {
    const int p = tid + i * 256;
    const int d = p & 63, g8 = p >> 6;
    u16 tmp[8];
    #pragma unroll
    for (int j = 0; j < 8; j++) tmp[j] = f2bf(ttile[d][g8 * 8 + j]);
    *(u32x4*)(qtbase + (size_t)(d0 + d) * QROW + jn0 + g8 * 8) = *(u32x4*)tmp;
  }
  __syncthreads();

  // ---- v epilogue: ttile[jn][e-local] -> padded V^T tile store ----
  #pragma unroll
  for (int mi = 0; mi < 2; mi++)
    #pragma unroll
    for (int ni = 0; ni < 2; ni++)
      *(f32x4*)&ttile[wn * 32 + ni * 16 + l15][wm * 32 + mi * 16 + quad * 4] = accv[mi][ni];
  __syncthreads();
  u16* vtbase = vtb + bh * (size_t)(32 * HN * VROW) + (size_t)dtile * (HN * VROW);
  #pragma unroll
  for (int i = 0; i < 2; i++) {
    const int p = tid + i * 256;
    const int jn = p & 63, e8 = p >> 6;
    u16 tmp[8];
    #pragma unroll
    for (int j = 0; j < 8; j++) tmp[j] = f2bf(ttile[jn][e8 * 8 + j]);
    *(u32x4*)(vtbase + (size_t)(jn0 + jn) * VROW + e8 * 8) = *(u32x4*)tmp;
  }
}

// ---------------------------------------------------------------------------
// Kernel 2: fused attention v4.  S^T = K·Q^T trick:
//   C-layout of S^T has d on lane&15, e on quad*4+r -> P writes are b64,
//   P buffer [d][e] reads back directly as the PV A-fragment.
//   p(d,e) = exp(2*S - q2[e] - q2[d]) (analytic max = diagonal).
// Block: 4 waves x 32 d-rows = 128 rows; grid 512 = 2 blocks/CU.
// All LDS layouts conflict-free via global-side padding (DMA-linear).
// ---------------------------------------------------------------------------
__global__ __launch_bounds__(256, 2) void attn_kernel(const u16* __restrict__ qkb,
                                                      const u16* __restrict__ vtb,
                                                      const float* __restrict__ q2,
                                                      u16* __restrict__ wbuf) {
  const int bid  = blockIdx.x;
  const int bh   = (bid & 7) * 4 + (bid >> 7);  // xcd*4 + sub: 4 bh per XCD
  const int dblk = (bid >> 3) & 15;             // 128-row block
  const int b = bh >> 2, h = bh & 3;
  const int tid  = threadIdx.x;
  const int wave = tid >> 6, lane = tid & 63;
  const int l15  = lane & 15, quad = lane >> 4;

  __shared__ u16 Klds[64 * QROW];        // 25.6 KB  [e][200]
  __shared__ u16 Vlds[HN * VROW];        // 27.6 KB  [jn][72]
  __shared__ u16 Plds[4][32][VROW];      // 18.4 KB  per-wave P [d][e(64)+pad]
  __shared__ float rsl[4][32];

  const u16* kg = qkb + (size_t)bh * (D_ * QROW);
  const u16* vg = vtb + (size_t)bh * (32 * HN * VROW);
  const float* q2g = q2 + (size_t)bh * D_;

  // Q B-fragments (n=d=lane&15, k=jn=quad*8+j), rows dblk*128+wave*32+nt*16+l15
  bf16x8 Qf[2][6];
  {
    const u16* qrow = kg + (size_t)(dblk * 128 + wave * 32 + l15) * QROW + quad * 8;
    #pragma unroll
    for (int nt = 0; nt < 2; nt++)
      #pragma unroll
      for (int f = 0; f < 6; f++)
        Qf[nt][f] = *(const bf16x8*)(qrow + (size_t)nt * 16 * QROW + f * 32);
  }
  float cd[2];
  cd[0] = q2g[dblk * 128 + wave * 32 + l15];
  cd[1] = q2g[dblk * 128 + wave * 32 + 16 + l15];

  const f32x4 fz = {0.f, 0.f, 0.f, 0.f};
  f32x4 O[2][12];
  #pragma unroll
  for (int mt = 0; mt < 2; mt++)
    #pragma unroll
    for (int c = 0; c < 12; c++) O[mt][c] = fz;
  float rsp[2] = {0.f, 0.f};

  for (int t = 0; t < 32; t++) {
    __syncthreads();   // all waves done reading previous K/V
    {
      const char* ks = (const char*)kg + (size_t)t * KTILE_B;
      char* kd = (char*)Klds;
      for (int c = wave; c < 25; c += 4)
        gld16(ks + c * 1024 + lane * 16, kd + c * 1024 + lane * 16);
      const char* vs = (const char*)vg + (size_t)t * VTILE_B;
      char* vd = (char*)Vlds;
      for (int c = wave; c < 27; c += 4)
        gld16(vs + c * 1024 + lane * 16, vd + c * 1024 + lane * 16);
    }
    __syncthreads();   // barrier's vmcnt(0) drains the DMA

    // ---- S^T = K Q^T per 16-e group; exp; b64 P writes ----
    #pragma unroll
    for (int et = 0; et < 4; et++) {
      bf16x8 Kf[6];
      #pragma unroll
      for (int f = 0; f < 6; f++)
        Kf[f] = *(const bf16x8*)&Klds[(et * 16 + l15) * QROW + f * 32 + quad * 8];
      f32x4 S0 = fz, S1 = fz;
      #pragma unroll
      for (int f = 0; f < 6; f++) {
        S0 = __builtin_amdgcn_mfma_f32_16x16x32_bf16(Kf[f], Qf[0][f], S0, 0, 0, 0);
        S1 = __builtin_amdgcn_mfma_f32_16x16x32_bf16(Kf[f], Qf[1][f], S1, 0, 0, 0);
      }
      const f32x4 ce = *(const f32x4*)&q2g[t * 64 + et * 16 + quad * 4];
      u16 pk0[4], pk1[4];
      #pragma unroll
      for (int r = 0; r < 4; r++) {
        float p0 = __expf(__builtin_fmaf(S0[r], 2.f, -(ce[r] + cd[0])));
        float p1 = __expf(__builtin_fmaf(S1[r], 2.f, -(ce[r] + cd[1])));
        rsp[0] += p0; rsp[1] += p1;
        pk0[r] = f2bf(p0); pk1[r] = f2bf(p1);
      }
      *(u32x2*)&Plds[wave][l15][et * 16 + quad * 4]      = *(u32x2*)pk0;
      *(u32x2*)&Plds[wave][16 + l15][et * 16 + quad * 4] = *(u32x2*)pk1;
    }

    // ---- O += P V (A=P from Plds, B=V from Vlds) ----
    #pragma unroll
    for (int kk = 0; kk < 2; kk++) {
      bf16x8 Pf0 = *(const bf16x8*)&Plds[wave][l15][kk * 32 + quad * 8];
      bf16x8 Pf1 = *(const bf16x8*)&Plds[wave][16 + l15][kk * 32 + quad * 8];
      #pragma unroll
      for (int c = 0; c < 12; c++) {
        bf16x8 Vf = *(const bf16x8*)&Vlds[(c * 16 + l15) * VROW + kk * 32 + quad * 8];
        O[0][c] = __builtin_amdgcn_mfma_f32_16x16x32_bf16(Pf0, Vf, O[0][c], 0, 0, 0);
        O[1][c] = __builtin_amdgcn_mfma_f32_16x16x32_bf16(Pf1, Vf, O[1][c], 0, 0, 0);
      }
    }
  }

  // row sums: reduce over quads (e-direction), publish via LDS
  #pragma unroll
  for (int nt = 0; nt < 2; nt++) {
    float s = rsp[nt];
    s += __shfl_xor(s, 16, 64);
    s += __shfl_xor(s, 32, 64);
    if (quad == 0) rsl[wave][nt * 16 + l15] = s;
  }
  __builtin_amdgcn_s_waitcnt(0);  // lgkm drain for wave-private LDS
  // normalize + merged-head store: wbuf[b, d, h*192 + col] bf16
  #pragma unroll
  for (int mt = 0; mt < 2; mt++)
    #pragma unroll
    for (int r = 0; r < 4; r++) {
      const float inv = 1.f / rsl[wave][mt * 16 + quad * 4 + r];
      const int d = dblk * 128 + wave * 32 + mt * 16 + quad * 4 + r;
      u16* wrow = wbuf + ((size_t)b * D_ + d) * N_ + h * HN;
      #pragma unroll
      for (int c = 0; c < 12; c++)
        wrow[c * 16 + l15] = f2bf(O[mt][c][r] * inv);
    }
}

// ---------------------------------------------------------------------------
// Kernel 3: out GEMM + transpose.  out[b,i,d] = sum_j w[b,d,j]*Wout[i,j] (fp32)
// ---------------------------------------------------------------------------
__global__ __launch_bounds__(256) void out_gemm(const u16* __restrict__ wbuf,
                                                const u16* __restrict__ wout,
                                                float* __restrict__ outp) {
  const int b  = blockIdx.z;
  const int d0 = blockIdx.x * 64;
  const int i0 = blockIdx.y * 64;
  const int tid  = threadIdx.x;
  const int wave = tid >> 6, lane = tid & 63;
  const int l15  = lane & 15, quad = lane >> 4;
  const int wm = wave >> 1, wn = wave & 1;

  __shared__ u16 At[64][40];
  __shared__ u16 Bt[64][40];
  __shared__ float otile[64][68];

  const f32x4 fz = {0.f, 0.f, 0.f, 0.f};
  f32x4 acc[2][2];
  #pragma unroll
  for (int i = 0; i < 2; i++)
    #pragma unroll
    for (int j = 0; j < 2; j++) acc[i][j] = fz;

  const int srow = tid >> 2;
  const int soff = (tid & 3) * 8;
  const u16* ax = wbuf + ((size_t)b * D_ + d0 + srow) * N_ + soff;
  const u16* bw = wout + (size_t)(i0 + srow) * N_ + soff;

  for (int k0 = 0; k0 < N_; k0 += 32) {
    __syncthreads();
    *(u32x4*)&At[srow][soff] = *(const u32x4*)(ax + k0);
    *(u32x4*)&Bt[srow][soff] = *(const u32x4*)(bw + k0);
    __syncthreads();
    bf16x8 Af[2], Bf[2];
    #pragma unroll
    for (int mi = 0; mi < 2; mi++)
      Af[mi] = *(const bf16x8*)&At[wm * 32 + mi * 16 + l15][quad * 8];
    #pragma unroll
    for (int ni = 0; ni < 2; ni++)
      Bf[ni] = *(const bf16x8*)&Bt[wn * 32 + ni * 16 + l15][quad * 8];
    #pragma unroll
    for (int mi = 0; mi < 2; mi++)
      #pragma unroll
      for (int ni = 0; ni < 2; ni++)
        acc[mi][ni] = __builtin_amdgcn_mfma_f32_16x16x32_bf16(Af[mi], Bf[ni], acc[mi][ni], 0, 0, 0);
  }

  #pragma unroll
  for (int mi = 0; mi < 2; mi++)
    #pragma unroll
    for (int ni = 0; ni < 2; ni++)
      #pragma unroll
      for (int r = 0; r < 4; r++)
        otile[wn * 32 + ni * 16 + l15][wm * 32 + mi * 16 + quad * 4 + r] = acc[mi][ni][r];
  __syncthreads();
  const int il = tid >> 2;
  const int ch = (tid & 3) * 16;
  float* orow = outp + ((size_t)b * N_ + i0 + il) * D_ + d0 + ch;
  #pragma unroll
  for (int i = 0; i < 16; i += 4)
    *(f32x4*)(orow + i) = *(const f32x4*)&otile[il][ch + i];
}

// ---------------------------------------------------------------------------
extern "C" void kernel_launch(void* const* d_in, const int* in_sizes, int n_in,
                              void* d_out, int out_size, void* d_ws, size_t ws_size,
                              hipStream_t stream) {
  (void)in_sizes; (void)n_in; (void)out_size; (void)ws_size;
  const float* x    = (const float*)d_in[0];
  const float* Wqk  = (const float*)d_in[1];
  const float* Wv   = (const float*)d_in[2];
  const float* Wout = (const float*)d_in[3];
  float* outp = (float*)d_out;

  // Workspace layout (~83.5 MB total; all offsets 16B-aligned)
  char* ws = (char*)d_ws;
  size_t off = 0;
  u16* xt   = (u16*)(ws + off); off += (size_t)B_ * D_ * N_ * 2;          // 25.2 MB
  u16* qkb  = (u16*)(ws + off); off += (size_t)B_ * H_ * D_ * QROW * 2;   // 26.2 MB
  u16* vtb  = (u16*)(ws + off); off += (size_t)B_ * H_ * 32 * HN * VROW * 2; // 28.3 MB
  float* q2 = (float*)(ws + off); off += (size_t)B_ * H_ * D_ * 4;        // 256 KB
  u16* wqk_bf  = (u16*)(ws + off); off += (size_t)N_ * N_ * 2;
  u16* wv_bf   = (u16*)(ws + off); off += (size_t)N_ * N_ * 2;
  u16* wout_bf = (u16*)(ws + off); off += (size_t)N_ * N_ * 2;
  u16* wbuf = xt;   // xt dead after qkv_gemm; reuse for attention output

  transpose_x<<<dim3(D_ / 64, N_ / 64, B_), 256, 0, stream>>>(x, xt);
  cvt_w<<<dim3((N_ * N_) / (256 * 4), 3), 256, 0, stream>>>(Wqk, Wv, Wout, wqk_bf, wv_bf, wout_bf);
  zero_q2<<<dim3((B_ * H_ * D_) / 256), 256, 0, stream>>>(q2);
  qkv_gemm<<<dim3(D_ / 64, N_ / 64, B_), 256, 0, stream>>>(xt, wqk_bf, wv_bf, qkb, vtb, q2);
  attn_kernel<<<dim3((D_ / 128) * B_ * H_), 256, 0, stream>>>(qkb, vtb, q2, wbuf);
  out_gemm<<<dim3(D_ / 64, N_ / 64, B_), 256, 0, stream>>>(wbuf, wout_bf, outp);
}